// Round 6
// baseline (700.502 us; speedup 1.0000x reference)
//
#include <hip/hip_runtime.h>
#include <math.h>

#define R_LOG2 13
#define R_BKT  8192      // constraints per bucket (32 KB LDS accumulator)
#define SLICE  16        // blocks per bucket in accumulate phase
#define MAXNB  64        // max buckets supported by fast path
#define WAVE_RECS 1024   // records per wave in partition

// ============================= fast path =============================

// probs = sigmoid(pred); zero bucket cursors and out.
__global__ void init_fast(const float* __restrict__ pred,
                          float* __restrict__ probs,
                          unsigned* __restrict__ cursor,
                          float* __restrict__ out,
                          int n_vars, int nb) {
    int i = blockIdx.x * blockDim.x + threadIdx.x;
    if (i < n_vars) probs[i] = 1.0f / (1.0f + expf(-pred[i]));
    if (i < nb) cursor[i] = 0;
    if (i == 0) out[0] = 0.0f;
}

// Phase 1, wave-decoupled: each wave sorts its private 1024 records by bucket
// in its own LDS region (histogram -> shfl scan -> scatter -> coalesced copy).
// NO __syncthreads anywhere: waves proceed independently, hiding each other's
// latency. Record: {lidx:13 in [31:16] | bf16(val):16}.
__global__ __launch_bounds__(256) void partition_kernel(
        const int* __restrict__ cidx, const int* __restrict__ vidx,
        const float* __restrict__ coeff, const float* __restrict__ probs,
        unsigned* __restrict__ cursor, unsigned* __restrict__ recs,
        int nnz4, int nb, unsigned cap) {
    __shared__ unsigned      sorted[4][WAVE_RECS];   // 16 KB
    __shared__ unsigned char sortedB[4][WAVE_RECS];  // 4 KB (bucket of each rec)
    __shared__ unsigned      lcur[4][MAXNB];         // hist, then running cursor
    __shared__ unsigned      bst[4][MAXNB + 1];      // segment starts
    __shared__ unsigned      gbs[4][MAXNB];          // reserved global bases

    const int tid  = threadIdx.x;
    const int w    = tid >> 6;
    const int lane = tid & 63;

    if (lane < MAXNB) lcur[w][lane] = 0;   // wave-private, in-order DS pipe

    // ---- compute this wave's 16 records/lane ----
    unsigned rw[16];
    unsigned bk[16];
    bool     gv[4];
    const unsigned vbase = blockIdx.x * 1024u + (unsigned)w * 256u;
    #pragma unroll
    for (int g = 0; g < 4; ++g) {
        unsigned v = vbase + (unsigned)g * 64u + (unsigned)lane;
        gv[g] = v < (unsigned)nnz4;
        if (gv[g]) {
            int4   c4 = ((const int4*)cidx)[v];
            int4   v4 = ((const int4*)vidx)[v];
            float4 w4 = ((const float4*)coeff)[v];
            int   cc[4] = {c4.x, c4.y, c4.z, c4.w};
            float vv[4] = {w4.x * probs[v4.x], w4.y * probs[v4.y],
                           w4.z * probs[v4.z], w4.w * probs[v4.w]};
            #pragma unroll
            for (int j = 0; j < 4; ++j) {
                int k = g * 4 + j;
                unsigned bits = __builtin_bit_cast(unsigned, vv[j]);
                bits += 0x7FFFu + ((bits >> 16) & 1u);     // RNE to bf16
                rw[k] = ((unsigned)(cc[j] & (R_BKT - 1)) << 16) | (bits >> 16);
                bk[k] = (unsigned)cc[j] >> R_LOG2;
            }
        }
    }

    // ---- wave-private histogram ----
    #pragma unroll
    for (int g = 0; g < 4; ++g) if (gv[g]) {
        #pragma unroll
        for (int j = 0; j < 4; ++j)
            atomicAdd(&lcur[w][bk[g * 4 + j]], 1u);
    }

    // ---- 64-lane inclusive scan via shfl (no barriers) ----
    unsigned cnt = (lane < nb) ? lcur[w][lane] : 0u;
    unsigned sc = cnt;
    #pragma unroll
    for (int d = 1; d < 64; d <<= 1) {
        unsigned t = __shfl_up(sc, d, 64);
        if (lane >= d) sc += t;
    }
    unsigned excl  = sc - cnt;
    unsigned total = __shfl(sc, nb - 1, 64);

    // reserve global space, set segment starts / running cursors
    if (lane < nb) {
        bst[w][lane]  = excl;
        gbs[w][lane]  = cnt ? atomicAdd(&cursor[lane], cnt) : 0u;
        lcur[w][lane] = excl;
    }
    if (lane == 0) bst[w][nb] = total;

    // ---- scatter into wave-private sorted region ----
    #pragma unroll
    for (int g = 0; g < 4; ++g) if (gv[g]) {
        #pragma unroll
        for (int j = 0; j < 4; ++j) {
            int k = g * 4 + j;
            unsigned pos = atomicAdd(&lcur[w][bk[k]], 1u);
            sorted[w][pos]  = rw[k];
            sortedB[w][pos] = (unsigned char)bk[k];
        }
    }

    // ---- coalesced copy-out (bucket id read directly, no search) ----
    for (unsigned p = (unsigned)lane; p < total; p += 64u) {
        unsigned r = sorted[w][p];
        unsigned b = sortedB[w][p];
        unsigned pos = gbs[w][b] + (p - bst[w][b]);
        if (pos < cap) recs[(size_t)b * cap + pos] = r;
    }
}

// Phase 2: block (b,s) accumulates slice s of bucket b into LDS via ds_add,
// vec4 record loads for MLP, then streams out a per-slice partial copy.
__global__ __launch_bounds__(256) void accum_kernel(
        const unsigned* __restrict__ recs, const unsigned* __restrict__ cursor,
        float* __restrict__ partial, int n_constrs, unsigned cap) {
    __shared__ float acc[R_BKT];
    const int b = blockIdx.x / SLICE;
    const int s = blockIdx.x % SLICE;
    for (int j = threadIdx.x * 4; j < R_BKT; j += blockDim.x * 4)
        *(float4*)(acc + j) = make_float4(0.f, 0.f, 0.f, 0.f);
    __syncthreads();

    unsigned cnt = cursor[b];
    if (cnt > cap) cnt = cap;
    const unsigned* base = recs + (size_t)b * cap;

    // vec4 body: slice the vec4-groups among SLICE blocks
    unsigned c4 = cnt >> 2;
    unsigned s4 = (unsigned)(((unsigned long long)c4 * s) / SLICE);
    unsigned e4 = (unsigned)(((unsigned long long)c4 * (s + 1)) / SLICE);
    const uint4* b4 = (const uint4*)base;
    #pragma unroll 2
    for (unsigned i = s4 + threadIdx.x; i < e4; i += blockDim.x) {
        uint4 r = b4[i];
        unsafeAtomicAdd(&acc[r.x >> 16], __builtin_bit_cast(float, (r.x & 0xFFFFu) << 16));
        unsafeAtomicAdd(&acc[r.y >> 16], __builtin_bit_cast(float, (r.y & 0xFFFFu) << 16));
        unsafeAtomicAdd(&acc[r.z >> 16], __builtin_bit_cast(float, (r.z & 0xFFFFu) << 16));
        unsafeAtomicAdd(&acc[r.w >> 16], __builtin_bit_cast(float, (r.w & 0xFFFFu) << 16));
    }
    // tail records (cnt not multiple of 4): last slice handles them
    if (s == SLICE - 1) {
        for (unsigned i = (c4 << 2) + threadIdx.x; i < cnt; i += blockDim.x) {
            unsigned r = base[i];
            unsafeAtomicAdd(&acc[r >> 16], __builtin_bit_cast(float, (r & 0xFFFFu) << 16));
        }
    }
    __syncthreads();

    const int gb = b * R_BKT;
    float* dst = partial + (size_t)s * n_constrs;
    for (int j = threadIdx.x * 4; j < R_BKT; j += blockDim.x * 4) {
        int g = gb + j;
        if (g < n_constrs)
            *(float4*)(dst + g) = make_float4(acc[j], acc[j+1], acc[j+2], acc[j+3]);
    }
}

// Phase 3: sum SLICE partials, violation by sense, mean.
__global__ void reduce_fast(const float* __restrict__ partial,
                            const float* __restrict__ rhs,
                            const int* __restrict__ sense,
                            float* __restrict__ out,
                            int n_constrs, float inv_n) {
    int i = blockIdx.x * blockDim.x + threadIdx.x;
    float v = 0.0f;
    if (i < n_constrs) {
        float a = 0.0f;
        #pragma unroll
        for (int s = 0; s < SLICE; ++s)
            a += partial[(size_t)s * n_constrs + i];
        float d = a - rhs[i];
        int sn = sense[i];
        v = (sn == 1) ? fmaxf(d, 0.0f)
          : (sn == 2) ? fmaxf(-d, 0.0f)
          : (sn == 3) ? fabsf(d)
          : 0.0f;
    }
    #pragma unroll
    for (int off = 32; off > 0; off >>= 1)
        v += __shfl_down(v, off, 64);
    __shared__ float wsum[4];
    int lane = threadIdx.x & 63;
    int wid  = threadIdx.x >> 6;
    if (lane == 0) wsum[wid] = v;
    __syncthreads();
    if (threadIdx.x == 0)
        atomicAdd(out, (wsum[0] + wsum[1] + wsum[2] + wsum[3]) * inv_n);
}

// ======================= fallback path (small ws) =======================

__global__ void init_kernel(const float* __restrict__ pred,
                            float* __restrict__ probs,
                            float* __restrict__ ax,
                            float* __restrict__ out,
                            int n_vars, int n_constrs) {
    int i = blockIdx.x * blockDim.x + threadIdx.x;
    if (i < n_vars) probs[i] = 1.0f / (1.0f + expf(-pred[i]));
    if (i < n_constrs) ax[i] = 0.0f;
    if (i == 0) out[0] = 0.0f;
}

__global__ void scatter_kernel(const int* __restrict__ cidx,
                               const int* __restrict__ vidx,
                               const float* __restrict__ coeff,
                               const float* __restrict__ probs,
                               float* __restrict__ ax,
                               int nnz) {
    int i = blockIdx.x * blockDim.x + threadIdx.x;
    long long base = (long long)i * 4;
    if (base + 3 < (long long)nnz) {
        int4   c = ((const int4*)cidx)[i];
        int4   v = ((const int4*)vidx)[i];
        float4 w = ((const float4*)coeff)[i];
        unsafeAtomicAdd(&ax[c.x], w.x * probs[v.x]);
        unsafeAtomicAdd(&ax[c.y], w.y * probs[v.y]);
        unsafeAtomicAdd(&ax[c.z], w.z * probs[v.z]);
        unsafeAtomicAdd(&ax[c.w], w.w * probs[v.w]);
    } else if (base < (long long)nnz) {
        for (long long k = base; k < (long long)nnz; ++k)
            unsafeAtomicAdd(&ax[cidx[k]], coeff[k] * probs[vidx[k]]);
    }
}

__global__ void reduce_kernel(const float* __restrict__ ax,
                              const float* __restrict__ rhs,
                              const int* __restrict__ sense,
                              float* __restrict__ out,
                              int n_constrs, float inv_n) {
    int i = blockIdx.x * blockDim.x + threadIdx.x;
    float v = 0.0f;
    if (i < n_constrs) {
        float d = ax[i] - rhs[i];
        int s = sense[i];
        v = (s == 1) ? fmaxf(d, 0.0f)
          : (s == 2) ? fmaxf(-d, 0.0f)
          : (s == 3) ? fabsf(d)
          : 0.0f;
    }
    #pragma unroll
    for (int off = 32; off > 0; off >>= 1)
        v += __shfl_down(v, off, 64);
    __shared__ float wsum[4];
    int lane = threadIdx.x & 63;
    int wid  = threadIdx.x >> 6;
    if (lane == 0) wsum[wid] = v;
    __syncthreads();
    if (threadIdx.x == 0)
        atomicAdd(out, (wsum[0] + wsum[1] + wsum[2] + wsum[3]) * inv_n);
}

// ============================== launch ==============================

static inline size_t align16(size_t x) { return (x + 15) & ~(size_t)15; }

extern "C" void kernel_launch(void* const* d_in, const int* in_sizes, int n_in,
                              void* d_out, int out_size, void* d_ws, size_t ws_size,
                              hipStream_t stream) {
    const float* pred  = (const float*)d_in[0];
    const int*   cidx  = (const int*)d_in[1];
    const int*   vidx  = (const int*)d_in[2];
    const float* coeff = (const float*)d_in[3];
    const float* rhs   = (const float*)d_in[4];
    const int*   sense = (const int*)d_in[5];

    const int n_vars    = in_sizes[0];
    const int nnz       = in_sizes[1];
    const int n_constrs = in_sizes[4];
    const int B = 256;
    const float inv_n = 1.0f / (float)n_constrs;

    const int nb = (n_constrs + R_BKT - 1) / R_BKT;
    unsigned cap = (unsigned)(((double)nnz * R_BKT / (double)n_constrs) * 1.0625) + 1024;
    cap = (cap + 3u) & ~3u;   // 16B alignment for uint4 loads in accum

    // fast-path workspace layout
    size_t off_probs  = 0;
    size_t off_cursor = align16(off_probs + (size_t)n_vars * 4);
    size_t off_recs   = align16(off_cursor + (size_t)nb * 4);
    size_t off_part   = align16(off_recs + (size_t)nb * cap * 4);
    size_t need_fast  = off_part + (size_t)SLICE * n_constrs * 4;

    bool fast = (ws_size >= need_fast) && (nb <= MAXNB) && ((nnz & 3) == 0);

    if (fast) {
        float*    probs   = (float*)((char*)d_ws + off_probs);
        unsigned* cursor  = (unsigned*)((char*)d_ws + off_cursor);
        unsigned* recs    = (unsigned*)((char*)d_ws + off_recs);
        float*    partial = (float*)((char*)d_ws + off_part);
        float*    out     = (float*)d_out;

        int init_n = n_vars > nb ? n_vars : nb;
        init_fast<<<(init_n + B - 1) / B, B, 0, stream>>>(
            pred, probs, cursor, out, n_vars, nb);

        int nnz4 = nnz >> 2;
        int nblk1 = (nnz4 + 1023) / 1024;          // 4096 records per block
        partition_kernel<<<nblk1, B, 0, stream>>>(
            cidx, vidx, coeff, probs, cursor, recs, nnz4, nb, cap);

        accum_kernel<<<nb * SLICE, B, 0, stream>>>(
            recs, cursor, partial, n_constrs, cap);

        reduce_fast<<<(n_constrs + B - 1) / B, B, 0, stream>>>(
            partial, rhs, sense, out, n_constrs, inv_n);
    } else {
        float* probs = (float*)d_ws;
        float* ax    = probs + n_vars;
        float* out   = (float*)d_out;

        int init_n = n_vars > n_constrs ? n_vars : n_constrs;
        init_kernel<<<(init_n + B - 1) / B, B, 0, stream>>>(
            pred, probs, ax, out, n_vars, n_constrs);

        int n_vec_threads = (nnz + 3) / 4;
        scatter_kernel<<<(n_vec_threads + B - 1) / B, B, 0, stream>>>(
            cidx, vidx, coeff, probs, ax, nnz);

        reduce_kernel<<<(n_constrs + B - 1) / B, B, 0, stream>>>(
            ax, rhs, sense, out, n_constrs, inv_n);
    }
}

// Round 7
// 499.208 us; speedup vs baseline: 1.4032x; 1.4032x over previous
//
#include <hip/hip_runtime.h>
#include <math.h>

#define R_LOG2 13
#define R_BKT  8192      // constraints per bucket (32 KB LDS accumulator)
#define SLICE  16        // blocks per bucket in accumulate phase
#define MAXNB  64        // max buckets supported by fast path
#define PB     512       // partition block size (8 waves)
#define BLK_RECS 8192    // records per partition block

// ============================= fast path =============================

// probs = sigmoid(pred) (float4); zero bucket cursors and out.
__global__ void init_fast(const float4* __restrict__ pred4,
                          float4* __restrict__ probs4,
                          unsigned* __restrict__ cursor,
                          float* __restrict__ out,
                          int n_vars4, int nb) {
    int i = blockIdx.x * blockDim.x + threadIdx.x;
    if (i < n_vars4) {
        float4 p = pred4[i];
        float4 q;
        q.x = 1.0f / (1.0f + expf(-p.x));
        q.y = 1.0f / (1.0f + expf(-p.y));
        q.z = 1.0f / (1.0f + expf(-p.z));
        q.w = 1.0f / (1.0f + expf(-p.w));
        probs4[i] = q;
    }
    if (i < nb) cursor[i] = 0;
    if (i == 0) out[0] = 0.0f;
}

// Phase 1: block counting-sort of 8192 records by bucket (cidx>>13).
// Wave-replicated histogram -> wave-0 shfl scan (replaces 16-barrier
// Hillis-Steele) -> LDS scatter -> per-bucket coalesced copy-out.
// Record: {lidx:13 in [31:16] | bf16(val):16}. 4 barriers total.
__global__ __launch_bounds__(PB) void partition_kernel(
        const int* __restrict__ cidx, const int* __restrict__ vidx,
        const float* __restrict__ coeff, const float* __restrict__ probs,
        unsigned* __restrict__ cursor, unsigned* __restrict__ recs,
        int nnz4, int nb, unsigned cap) {
    __shared__ unsigned sorted[BLK_RECS];     // 32 KB
    __shared__ unsigned hist[MAXNB * 8];      // [b*8 + wave] 2 KB
    __shared__ unsigned lcur[MAXNB * 8];      // running cursors 2 KB
    __shared__ unsigned bst[MAXNB + 1];       // bucket starts in sorted[]
    __shared__ unsigned gbs[MAXNB];           // reserved global bases

    const int tid  = threadIdx.x;
    const int w    = tid >> 6;                // wave 0..7
    const int lane = tid & 63;

    hist[tid] = 0;                            // 512 counters, 512 threads

    // ---- compute this thread's 16 records ----
    unsigned rw[16];
    unsigned bk[16];
    bool     gv[4];
    #pragma unroll
    for (int g = 0; g < 4; ++g) {
        unsigned v = blockIdx.x * (BLK_RECS / 4) + g * PB + (unsigned)tid;
        gv[g] = v < (unsigned)nnz4;
        if (gv[g]) {
            int4   c4 = ((const int4*)cidx)[v];
            int4   v4 = ((const int4*)vidx)[v];
            float4 w4 = ((const float4*)coeff)[v];
            int   cc[4] = {c4.x, c4.y, c4.z, c4.w};
            float vv[4] = {w4.x * probs[v4.x], w4.y * probs[v4.y],
                           w4.z * probs[v4.z], w4.w * probs[v4.w]};
            #pragma unroll
            for (int j = 0; j < 4; ++j) {
                int k = g * 4 + j;
                unsigned bits = __builtin_bit_cast(unsigned, vv[j]);
                bits += 0x7FFFu + ((bits >> 16) & 1u);     // RNE to bf16
                rw[k] = ((unsigned)(cc[j] & (R_BKT - 1)) << 16) | (bits >> 16);
                bk[k] = (unsigned)cc[j] >> R_LOG2;
            }
        }
    }
    __syncthreads();

    // ---- pass A: wave-replicated histogram ----
    #pragma unroll
    for (int g = 0; g < 4; ++g) if (gv[g]) {
        #pragma unroll
        for (int j = 0; j < 4; ++j)
            atomicAdd(&hist[bk[g * 4 + j] * 8 + w], 1u);
    }
    __syncthreads();

    // ---- wave-0: scan bucket totals, set cursors, reserve global space ----
    if (w == 0) {
        unsigned h[8];
        unsigned cnt = 0;
        if (lane < nb) {
            #pragma unroll
            for (int j = 0; j < 8; ++j) { h[j] = hist[lane * 8 + j]; cnt += h[j]; }
        }
        unsigned sc = cnt;
        #pragma unroll
        for (int d = 1; d < 64; d <<= 1) {
            unsigned t = __shfl_up(sc, d, 64);
            if (lane >= d) sc += t;
        }
        unsigned excl  = sc - cnt;
        unsigned total = __shfl(sc, nb - 1, 64);
        if (lane < nb) {
            bst[lane] = excl;
            unsigned run = excl;
            #pragma unroll
            for (int j = 0; j < 8; ++j) { lcur[lane * 8 + j] = run; run += h[j]; }
            gbs[lane] = cnt ? atomicAdd(&cursor[lane], cnt) : 0u;
        }
        if (lane == 0) bst[nb] = total;
    }
    __syncthreads();

    // ---- pass B: scatter into sorted LDS ----
    #pragma unroll
    for (int g = 0; g < 4; ++g) if (gv[g]) {
        #pragma unroll
        for (int j = 0; j < 4; ++j) {
            int k = g * 4 + j;
            unsigned pos = atomicAdd(&lcur[bk[k] * 8 + w], 1u);
            sorted[pos] = rw[k];
        }
    }
    __syncthreads();

    // ---- copy-out: wave w handles buckets w, w+8, ... (contiguous both sides) ----
    for (int b = w; b < nb; b += 8) {
        unsigned st = bst[b], en = bst[b + 1], gb = gbs[b];
        unsigned* dst = recs + (size_t)b * cap;
        for (unsigned p = st + (unsigned)lane; p < en; p += 64u) {
            unsigned pos = gb + (p - st);
            if (pos < cap) dst[pos] = sorted[p];
        }
    }
}

// Phase 2: block (b,s) accumulates slice s of bucket b into LDS via ds_add,
// vec4 record loads for MLP, then streams out a per-slice partial copy.
__global__ __launch_bounds__(256) void accum_kernel(
        const unsigned* __restrict__ recs, const unsigned* __restrict__ cursor,
        float* __restrict__ partial, int n_constrs, unsigned cap) {
    __shared__ float acc[R_BKT];
    const int b = blockIdx.x / SLICE;
    const int s = blockIdx.x % SLICE;
    for (int j = threadIdx.x * 4; j < R_BKT; j += blockDim.x * 4)
        *(float4*)(acc + j) = make_float4(0.f, 0.f, 0.f, 0.f);
    __syncthreads();

    unsigned cnt = cursor[b];
    if (cnt > cap) cnt = cap;
    const unsigned* base = recs + (size_t)b * cap;

    unsigned c4 = cnt >> 2;
    unsigned s4 = (unsigned)(((unsigned long long)c4 * s) / SLICE);
    unsigned e4 = (unsigned)(((unsigned long long)c4 * (s + 1)) / SLICE);
    const uint4* b4 = (const uint4*)base;
    #pragma unroll 2
    for (unsigned i = s4 + threadIdx.x; i < e4; i += blockDim.x) {
        uint4 r = b4[i];
        unsafeAtomicAdd(&acc[r.x >> 16], __builtin_bit_cast(float, (r.x & 0xFFFFu) << 16));
        unsafeAtomicAdd(&acc[r.y >> 16], __builtin_bit_cast(float, (r.y & 0xFFFFu) << 16));
        unsafeAtomicAdd(&acc[r.z >> 16], __builtin_bit_cast(float, (r.z & 0xFFFFu) << 16));
        unsafeAtomicAdd(&acc[r.w >> 16], __builtin_bit_cast(float, (r.w & 0xFFFFu) << 16));
    }
    if (s == SLICE - 1) {
        for (unsigned i = (c4 << 2) + threadIdx.x; i < cnt; i += blockDim.x) {
            unsigned r = base[i];
            unsafeAtomicAdd(&acc[r >> 16], __builtin_bit_cast(float, (r & 0xFFFFu) << 16));
        }
    }
    __syncthreads();

    const int gb = b * R_BKT;
    float* dst = partial + (size_t)s * n_constrs;
    for (int j = threadIdx.x * 4; j < R_BKT; j += blockDim.x * 4) {
        int g = gb + j;
        if (g < n_constrs)
            *(float4*)(dst + g) = make_float4(acc[j], acc[j+1], acc[j+2], acc[j+3]);
    }
}

// Phase 3: sum SLICE partials, violation by sense, mean.
__global__ void reduce_fast(const float* __restrict__ partial,
                            const float* __restrict__ rhs,
                            const int* __restrict__ sense,
                            float* __restrict__ out,
                            int n_constrs, float inv_n) {
    int i = blockIdx.x * blockDim.x + threadIdx.x;
    float v = 0.0f;
    if (i < n_constrs) {
        float a = 0.0f;
        #pragma unroll
        for (int s = 0; s < SLICE; ++s)
            a += partial[(size_t)s * n_constrs + i];
        float d = a - rhs[i];
        int sn = sense[i];
        v = (sn == 1) ? fmaxf(d, 0.0f)
          : (sn == 2) ? fmaxf(-d, 0.0f)
          : (sn == 3) ? fabsf(d)
          : 0.0f;
    }
    #pragma unroll
    for (int off = 32; off > 0; off >>= 1)
        v += __shfl_down(v, off, 64);
    __shared__ float wsum[4];
    int lane = threadIdx.x & 63;
    int wid  = threadIdx.x >> 6;
    if (lane == 0) wsum[wid] = v;
    __syncthreads();
    if (threadIdx.x == 0)
        atomicAdd(out, (wsum[0] + wsum[1] + wsum[2] + wsum[3]) * inv_n);
}

// ======================= fallback path (small ws) =======================

__global__ void init_kernel(const float* __restrict__ pred,
                            float* __restrict__ probs,
                            float* __restrict__ ax,
                            float* __restrict__ out,
                            int n_vars, int n_constrs) {
    int i = blockIdx.x * blockDim.x + threadIdx.x;
    if (i < n_vars) probs[i] = 1.0f / (1.0f + expf(-pred[i]));
    if (i < n_constrs) ax[i] = 0.0f;
    if (i == 0) out[0] = 0.0f;
}

__global__ void scatter_kernel(const int* __restrict__ cidx,
                               const int* __restrict__ vidx,
                               const float* __restrict__ coeff,
                               const float* __restrict__ probs,
                               float* __restrict__ ax,
                               int nnz) {
    int i = blockIdx.x * blockDim.x + threadIdx.x;
    long long base = (long long)i * 4;
    if (base + 3 < (long long)nnz) {
        int4   c = ((const int4*)cidx)[i];
        int4   v = ((const int4*)vidx)[i];
        float4 w = ((const float4*)coeff)[i];
        unsafeAtomicAdd(&ax[c.x], w.x * probs[v.x]);
        unsafeAtomicAdd(&ax[c.y], w.y * probs[v.y]);
        unsafeAtomicAdd(&ax[c.z], w.z * probs[v.z]);
        unsafeAtomicAdd(&ax[c.w], w.w * probs[v.w]);
    } else if (base < (long long)nnz) {
        for (long long k = base; k < (long long)nnz; ++k)
            unsafeAtomicAdd(&ax[cidx[k]], coeff[k] * probs[vidx[k]]);
    }
}

__global__ void reduce_kernel(const float* __restrict__ ax,
                              const float* __restrict__ rhs,
                              const int* __restrict__ sense,
                              float* __restrict__ out,
                              int n_constrs, float inv_n) {
    int i = blockIdx.x * blockDim.x + threadIdx.x;
    float v = 0.0f;
    if (i < n_constrs) {
        float d = ax[i] - rhs[i];
        int s = sense[i];
        v = (s == 1) ? fmaxf(d, 0.0f)
          : (s == 2) ? fmaxf(-d, 0.0f)
          : (s == 3) ? fabsf(d)
          : 0.0f;
    }
    #pragma unroll
    for (int off = 32; off > 0; off >>= 1)
        v += __shfl_down(v, off, 64);
    __shared__ float wsum[4];
    int lane = threadIdx.x & 63;
    int wid  = threadIdx.x >> 6;
    if (lane == 0) wsum[wid] = v;
    __syncthreads();
    if (threadIdx.x == 0)
        atomicAdd(out, (wsum[0] + wsum[1] + wsum[2] + wsum[3]) * inv_n);
}

// ============================== launch ==============================

static inline size_t align16(size_t x) { return (x + 15) & ~(size_t)15; }

extern "C" void kernel_launch(void* const* d_in, const int* in_sizes, int n_in,
                              void* d_out, int out_size, void* d_ws, size_t ws_size,
                              hipStream_t stream) {
    const float* pred  = (const float*)d_in[0];
    const int*   cidx  = (const int*)d_in[1];
    const int*   vidx  = (const int*)d_in[2];
    const float* coeff = (const float*)d_in[3];
    const float* rhs   = (const float*)d_in[4];
    const int*   sense = (const int*)d_in[5];

    const int n_vars    = in_sizes[0];
    const int nnz       = in_sizes[1];
    const int n_constrs = in_sizes[4];
    const int B = 256;
    const float inv_n = 1.0f / (float)n_constrs;

    const int nb = (n_constrs + R_BKT - 1) / R_BKT;
    unsigned cap = (unsigned)(((double)nnz * R_BKT / (double)n_constrs) * 1.0625) + 1024;
    cap = (cap + 3u) & ~3u;   // 16B alignment for uint4 loads in accum

    // fast-path workspace layout
    size_t off_probs  = 0;
    size_t off_cursor = align16(off_probs + (size_t)n_vars * 4);
    size_t off_recs   = align16(off_cursor + (size_t)nb * 4);
    size_t off_part   = align16(off_recs + (size_t)nb * cap * 4);
    size_t need_fast  = off_part + (size_t)SLICE * n_constrs * 4;

    bool fast = (ws_size >= need_fast) && (nb <= MAXNB) && ((nnz & 3) == 0)
             && ((n_vars & 3) == 0);

    if (fast) {
        float*    probs   = (float*)((char*)d_ws + off_probs);
        unsigned* cursor  = (unsigned*)((char*)d_ws + off_cursor);
        unsigned* recs    = (unsigned*)((char*)d_ws + off_recs);
        float*    partial = (float*)((char*)d_ws + off_part);
        float*    out     = (float*)d_out;

        int n_vars4 = n_vars >> 2;
        int init_n  = n_vars4 > nb ? n_vars4 : nb;
        init_fast<<<(init_n + B - 1) / B, B, 0, stream>>>(
            (const float4*)pred, (float4*)probs, cursor, out, n_vars4, nb);

        int nnz4 = nnz >> 2;
        int nblk1 = (nnz4 + (BLK_RECS / 4) - 1) / (BLK_RECS / 4);
        partition_kernel<<<nblk1, PB, 0, stream>>>(
            cidx, vidx, coeff, probs, cursor, recs, nnz4, nb, cap);

        accum_kernel<<<nb * SLICE, B, 0, stream>>>(
            recs, cursor, partial, n_constrs, cap);

        reduce_fast<<<(n_constrs + B - 1) / B, B, 0, stream>>>(
            partial, rhs, sense, out, n_constrs, inv_n);
    } else {
        float* probs = (float*)d_ws;
        float* ax    = probs + n_vars;
        float* out   = (float*)d_out;

        int init_n = n_vars > n_constrs ? n_vars : n_constrs;
        init_kernel<<<(init_n + B - 1) / B, B, 0, stream>>>(
            pred, probs, ax, out, n_vars, n_constrs);

        int n_vec_threads = (nnz + 3) / 4;
        scatter_kernel<<<(n_vec_threads + B - 1) / B, B, 0, stream>>>(
            cidx, vidx, coeff, probs, ax, nnz);

        reduce_kernel<<<(n_constrs + B - 1) / B, B, 0, stream>>>(
            ax, rhs, sense, out, n_constrs, inv_n);
    }
}